// Round 8
// baseline (522.025 us; speedup 1.0000x reference)
//
#include <hip/hip_runtime.h>

#define DEV __device__ __forceinline__

typedef short bf16x8 __attribute__((ext_vector_type(8)));
typedef float f32x4 __attribute__((ext_vector_type(4)));
typedef unsigned short u16;
typedef unsigned int u32;
typedef unsigned long long u64;

typedef __attribute__((address_space(3))) void lds_void;
typedef __attribute__((address_space(1))) void gbl_void;

DEV void async_copy16(void* lds_dst, const void* g_src) {
    __builtin_amdgcn_global_load_lds((gbl_void*)g_src, (lds_void*)lds_dst, 16, 0, 0);
}

DEV u16 f2bf(float x) {
    u32 u = __float_as_uint(x);
    return (u16)((u + 0x7fffu + ((u >> 16) & 1u)) >> 16);
}
DEV u16 f2bf_fast(float x) {  // x >= 0, finite
    return (u16)((__float_as_uint(x) + 0x8000u) >> 16);
}
DEV float bf2f(u16 v) { return __uint_as_float(((u32)v) << 16); }

// ---------------------------------------------------------------------------
// PREP mega-kernel: one dispatch replacing {zero, rowlist, f2bf x4, lnspan}.
// ---------------------------------------------------------------------------
__global__ __launch_bounds__(256) void prep_kernel(
    const float* __restrict__ we, const int* __restrict__ sb,
    const int* __restrict__ ss, const int* __restrict__ stg,
    const float* __restrict__ tag_emb, const float* __restrict__ gate_w,
    const float* __restrict__ gate_b, const float* __restrict__ g,
    const float* __restrict__ bta,
    const float* __restrict__ w0, const float* __restrict__ w1,
    const float* __restrict__ w2, const float* __restrict__ w3,
    u16* __restrict__ oe_bf, u16* __restrict__ o0, u16* __restrict__ o1,
    u16* __restrict__ o2, u16* __restrict__ o3) {
    const int blk = blockIdx.x;
    const int t = threadIdx.x;

    if (blk >= 8192) {  // ---- weight f2bf segments ----
        int base = blk - 8192;
        const float* src; u16* dst;
        if (base < 3072)      { src = w0; dst = o0; }
        else if (base < 4096) { src = w1; dst = o1; base -= 3072; }
        else if (base < 8192) { src = w2; dst = o2; base -= 4096; }
        else                  { src = w3; dst = o3; base -= 8192; }
        const int i = base * 256 + t;
        const float4 v = ((const float4*)src)[i];
        ushort4 o;
        o.x = f2bf(v.x); o.y = f2bf(v.y); o.z = f2bf(v.z); o.w = f2bf(v.w);
        ((ushort4*)dst)[i] = o;
        return;
    }

    // ---- lnspan ----
    __shared__ float red[8];
    __shared__ u64 smask[8];
    const int row = blk;
    const int b = row >> 10;
    const int s = row & 1023;

    {   // span scan: thread t checks spans t and t+256
        const bool m0 = (sb[t] == b) && ((u32)(s - ss[t]) < 32u);
        const bool m1 = (sb[t + 256] == b) && ((u32)(s - ss[t + 256]) < 32u);
        const u64 b0 = __ballot(m0);
        const u64 b1 = __ballot(m1);
        if ((t & 63) == 0) { smask[t >> 6] = b0; smask[4 + (t >> 6)] = b1; }
    }

    float4 x = ((const float4*)(we + (long)row * 1024))[t];
    const float4 gw = ((const float4*)gate_w)[t];
    float dot;
    {   // RoPE pairs p0=2t, p1=2t+1; dot with gate_w
        const float p0 = (float)(2 * t);
        const float p1 = (float)(2 * t + 1);
        const float inv0 = exp2f(p0 * (-13.287712379549449f / 512.0f));
        const float inv1 = exp2f(p1 * (-13.287712379549449f / 512.0f));
        const float a0 = (float)s * inv0, a1 = (float)s * inv1;
        const float s0 = sinf(a0), c0 = cosf(a0);
        const float s1 = sinf(a1), c1 = cosf(a1);
        const float r1a = x.x * c0 - x.y * s0, r2a = x.x * s0 + x.y * c0;
        const float r1b = x.z * c1 - x.w * s1, r2b = x.z * s1 + x.w * c1;
        dot = r1a * gw.x + r2a * gw.y + r1b * gw.z + r2b * gw.w;
    }
#pragma unroll
    for (int off = 32; off > 0; off >>= 1) dot += __shfl_xor(dot, off, 64);
    if ((t & 63) == 0) red[t >> 6] = dot;
    __syncthreads();  // red + smask visible
    const float z = red[0] + red[1] + red[2] + red[3] + gate_b[0];
    const float gate = 0.25f + 0.5f / (1.f + __expf(-z));
    const float coef = gate * 16.f;  // L * TAG_RATE * gate

    float4 add = {0.f, 0.f, 0.f, 0.f};
#pragma unroll
    for (int gi = 0; gi < 8; ++gi) {
        u64 m = smask[gi];
        const int nb = (gi & 3) * 64 + (gi >> 2) * 256;
        while (m) {
            const int bit = __ffsll(m) - 1;
            m &= m - 1;
            const int tag = stg[nb + bit];
            const float4 te = ((const float4*)(tag_emb + (long)tag * 1024))[t];
            add.x += te.x; add.y += te.y; add.z += te.z; add.w += te.w;
        }
    }
    x.x += coef * add.x; x.y += coef * add.y;
    x.z += coef * add.z; x.w += coef * add.w;

    // LayerNorm (eps = 1e-12)
    __syncthreads();
    float sm = x.x + x.y + x.z + x.w;
#pragma unroll
    for (int off = 32; off > 0; off >>= 1) sm += __shfl_xor(sm, off, 64);
    if ((t & 63) == 0) red[t >> 6] = sm;
    __syncthreads();
    const float mean = (red[0] + red[1] + red[2] + red[3]) * (1.f / 1024.f);
    float4 dx;
    dx.x = x.x - mean; dx.y = x.y - mean; dx.z = x.z - mean; dx.w = x.w - mean;
    float ss2 = dx.x * dx.x + dx.y * dx.y + dx.z * dx.z + dx.w * dx.w;
#pragma unroll
    for (int off = 32; off > 0; off >>= 1) ss2 += __shfl_xor(ss2, off, 64);
    if ((t & 63) == 0) red[4 + (t >> 6)] = ss2;
    __syncthreads();
    const float var = (red[4] + red[5] + red[6] + red[7]) * (1.f / 1024.f);
    const float rstd = rsqrtf(var + 1e-12f);
    const float4 gv = ((const float4*)g)[t];
    const float4 bv = ((const float4*)bta)[t];
    ushort4 o;
    o.x = f2bf(dx.x * rstd * gv.x + bv.x);
    o.y = f2bf(dx.y * rstd * gv.y + bv.y);
    o.z = f2bf(dx.z * rstd * gv.z + bv.z);
    o.w = f2bf(dx.w * rstd * gv.w + bv.w);
    ((ushort4*)(oe_bf + (long)row * 1024))[t] = o;
}

// ---------------------------------------------------------------------------
// LayerNorm over D=1024, one block per row.
// ---------------------------------------------------------------------------
template <bool WRITE_F32, bool WRITE_BF, bool FINAL>
__global__ __launch_bounds__(256) void ln_kernel(
    const float* __restrict__ X, const float* __restrict__ g,
    const float* __restrict__ bta, float eps, float* __restrict__ Yf,
    u16* __restrict__ Ybf, const u16* __restrict__ addend) {
    __shared__ float red[8];
    const long row = blockIdx.x;
    const int t = threadIdx.x;
    const float4 x = ((const float4*)(X + row * 1024))[t];
    float s = x.x + x.y + x.z + x.w;
#pragma unroll
    for (int off = 32; off > 0; off >>= 1) s += __shfl_xor(s, off, 64);
    if ((t & 63) == 0) red[t >> 6] = s;
    __syncthreads();
    const float mean = (red[0] + red[1] + red[2] + red[3]) * (1.f / 1024.f);
    float4 dx;
    dx.x = x.x - mean; dx.y = x.y - mean; dx.z = x.z - mean; dx.w = x.w - mean;
    float ss = dx.x * dx.x + dx.y * dx.y + dx.z * dx.z + dx.w * dx.w;
#pragma unroll
    for (int off = 32; off > 0; off >>= 1) ss += __shfl_xor(ss, off, 64);
    if ((t & 63) == 0) red[4 + (t >> 6)] = ss;
    __syncthreads();
    const float var = (red[4] + red[5] + red[6] + red[7]) * (1.f / 1024.f);
    const float rstd = rsqrtf(var + eps);
    const float4 gv = ((const float4*)g)[t];
    const float4 bv = ((const float4*)bta)[t];
    float4 y;
    y.x = dx.x * rstd * gv.x + bv.x;
    y.y = dx.y * rstd * gv.y + bv.y;
    y.z = dx.z * rstd * gv.z + bv.z;
    y.w = dx.w * rstd * gv.w + bv.w;
    if (FINAL) {
        const ushort4 a = ((const ushort4*)(addend + row * 1024))[t];
        y.x += bf2f(a.x); y.y += bf2f(a.y); y.z += bf2f(a.z); y.w += bf2f(a.w);
    }
    if (WRITE_F32) ((float4*)(Yf + row * 1024))[t] = y;
    if (WRITE_BF) {
        ushort4 o;
        o.x = f2bf(y.x); o.y = f2bf(y.y); o.z = f2bf(y.z); o.w = f2bf(y.w);
        ((ushort4*)(Ybf + row * 1024))[t] = o;
    }
}

// ---------------------------------------------------------------------------
// NT GEMM (measured-best 2-barrier structure; kept for N=1024 shapes).
// ---------------------------------------------------------------------------
template <bool OUT_BF16, bool RELU, bool HAS_RES, bool VTRANS>
__global__ __launch_bounds__(256, 2) void gemm_nt(
    const u16* __restrict__ A, const u16* __restrict__ B,
    const float* __restrict__ bias, const u16* __restrict__ res,
    void* __restrict__ Cout, int N, int K, u16* __restrict__ vt) {
    __shared__ u16 Al[8192];   // 128 rows x 64 k = 16 KB
    __shared__ u16 Bl[8192];
    const int tid = threadIdx.x;
    const int wave = tid >> 6;
    const int lane = tid & 63;
    const int quad = lane >> 4;
    const int lq = lane & 15;
    const int wm = wave >> 1;
    const int wn = wave & 1;
    const long rowBase = (long)blockIdx.x * 128;
    const long colBase = (long)blockIdx.y * 128;

    f32x4 acc[4][4];
    const f32x4 fzero = {0.f, 0.f, 0.f, 0.f};
#pragma unroll
    for (int i = 0; i < 4; ++i)
#pragma unroll
        for (int j = 0; j < 4; ++j) acc[i][j] = fzero;

    const int rX = tid >> 3;
    const int pX = (tid & 7) ^ (rX & 7);
    const u16* gA = A + (rowBase + rX) * (long)K + pX * 8;
    const u16* gB = B + (colBase + rX) * (long)K + pX * 8;
    u16* ldsA = Al + wave * 512;
    u16* ldsB = Bl + wave * 512;

    for (int kt = 0; kt < K; kt += 64) {
        __syncthreads();
#pragma unroll
        for (int c = 0; c < 4; ++c) {
            async_copy16(ldsA + c * 2048, gA + (long)c * 32 * K + kt);
            async_copy16(ldsB + c * 2048, gB + (long)c * 32 * K + kt);
        }
        __syncthreads();
#pragma unroll
        for (int ks = 0; ks < 2; ++ks) {
            bf16x8 af[4], bfr[4];
#pragma unroll
            for (int i = 0; i < 4; ++i) {
                const int r = wm * 64 + i * 16 + lq;
                af[i] = *(const bf16x8*)&Al[r * 64 + (((ks * 4 + quad) ^ (lq & 7)) * 8)];
            }
#pragma unroll
            for (int j = 0; j < 4; ++j) {
                const int r = wn * 64 + j * 16 + lq;
                bfr[j] = *(const bf16x8*)&Bl[r * 64 + (((ks * 4 + quad) ^ (lq & 7)) * 8)];
            }
#pragma unroll
            for (int i = 0; i < 4; ++i)
#pragma unroll
                for (int j = 0; j < 4; ++j)
                    acc[i][j] = __builtin_amdgcn_mfma_f32_16x16x32_bf16(
                        af[i], bfr[j], acc[i][j], 0, 0, 0);
        }
    }

    float biasv[4];
#pragma unroll
    for (int j = 0; j < 4; ++j) biasv[j] = bias[colBase + wn * 64 + j * 16 + lq];
#pragma unroll
    for (int i = 0; i < 4; ++i) {
        const long grow = rowBase + wm * 64 + i * 16 + quad * 4;
#pragma unroll
        for (int j = 0; j < 4; ++j) {
            const long gcol = colBase + wn * 64 + j * 16 + lq;
#pragma unroll
            for (int r = 0; r < 4; ++r) {
                float v = acc[i][j][r] + biasv[j];
                if (RELU) v = fmaxf(v, 0.f);
                if (HAS_RES) v += bf2f(res[(grow + r) * N + gcol]);
                if (VTRANS && gcol >= 2048) {
                    const int hh = (int)(gcol - 2048) >> 6;
                    const int dd = (int)(gcol - 2048) & 63;
                    const long rr = grow + r;
                    const int bb = (int)(rr >> 10);
                    const int sR = (int)(rr & 1023);
                    vt[(((long)bb * 16 + hh) * 64 + dd) * 1024 + sR] = f2bf(v);
                } else if (OUT_BF16) {
                    ((u16*)Cout)[(grow + r) * N + gcol] = f2bf(v);
                } else {
                    ((float*)Cout)[(grow + r) * N + gcol] = v;
                }
            }
        }
    }
}

// ---------------------------------------------------------------------------
// 256x256 8-phase GEMM, attempt 3 — asm hygiene per the m201 template:
//  * closing barriers = bare __builtin_amdgcn_s_barrier() (NOT "memory"-
//    clobbered asm: the clobber forces the waitcnt legalizer to drain
//    vmcnt(0) at every phase boundary, which silently serialized r3).
//  * waitcnts = bare asm volatile (no clobber).
//  * sched_barrier(0) ONLY after the two counted vmcnt points (rule #18
//    fence: blocks next-buffer ds_reads hoisting above the drain that
//    covers them). Not per-phase (m141: full pinning = -40%).
// Geometry (r3): 8 waves 2Mx4N, per-wave 128x64 = acc[8][4]; 64 MFMA per
// K-tile per wave over 24 ds_read_b128 (ratio 2.67); dbuf 128 KiB; XOR slot
// swizzle. Stage schedule: P1:A0(T1) P2:A1(T1) P3:B0(T2) P4:B1(T2)+vmcnt(4)
// P5:A0(T2) P6:A1(T2) P7:B0(T3) P8:B1(T3)+vmcnt(4).
// WAR safety: each phase's ds_reads are followed by that wave's lgkmcnt(0)
// before its MFMAs; the closing barrier then guarantees all waves' reads
// are complete before any wave issues the next phase's stage.
// ---------------------------------------------------------------------------
template <bool RELU, bool VTRANS>
__global__ __launch_bounds__(512, 2) void gemm_nt8(
    const u16* __restrict__ A, const u16* __restrict__ B,
    const float* __restrict__ bias, u16* __restrict__ Cout, int N, int K,
    u16* __restrict__ vt) {
    __shared__ u16 Al[2][16384];  // [buf][256 rows x 64 k]
    __shared__ u16 Bl[2][16384];
    const int tid = threadIdx.x;
    const int wave = tid >> 6;
    const int lane = tid & 63;
    const int quad = lane >> 4;
    const int lq = lane & 15;
    const int lq7 = lq & 7;
    const int wm = wave >> 2;  // 0..1 : 128-row band
    const int wn = wave & 3;   // 0..3 : 64-col band
    const long rowBase = (long)blockIdx.x * 256;
    const long colBase = (long)blockIdx.y * 256;
    const int NT = K >> 6;

    const int rs = tid >> 3;
    const int js = (tid & 7) ^ (rs & 7);
    const u16* gA = A + (rowBase + rs) * (long)K + js * 8;
    const u16* gB = B + (colBase + rs) * (long)K + js * 8;

    f32x4 acc[8][4];
    const f32x4 fz = {0.f, 0.f, 0.f, 0.f};
#pragma unroll
    for (int i = 0; i < 8; ++i)
#pragma unroll
        for (int j = 0; j < 4; ++j) acc[i][j] = fz;

    auto stA = [&](int buf, int h, int t) {
        u16* d = &Al[buf][h * 8192 + wave * 512];
        const u16* s = gA + (long)h * 128 * K + (long)t * 64;
        async_copy16(d, s);
        async_copy16(d + 4096, s + (long)64 * K);
    };
    auto stB = [&](int buf, int h, int t) {
        u16* d = &Bl[buf][h * 8192 + wave * 512];
        const u16* s = gB + (long)h * 128 * K + (long)t * 64;
        async_copy16(d, s);
        async_copy16(d + 4096, s + (long)64 * K);
    };
    auto ldA = [&](int buf, int i, int kh) {
        const int r = wm * 128 + i * 16 + lq;
        return *(const bf16x8*)&Al[buf][r * 64 + ((((kh << 2) | quad) ^ lq7) << 3)];
    };
    auto ldB = [&](int buf, int j, int kh) {
        const int r = wn * 64 + j * 16 + lq;
        return *(const bf16x8*)&Bl[buf][r * 64 + ((((kh << 2) | quad) ^ lq7) << 3)];
    };

#define PH_SYNC()                               \
    do {                                        \
        __builtin_amdgcn_s_barrier();           \
        asm volatile("s_waitcnt lgkmcnt(0)");   \
    } while (0)

    // prologue: T0 complete (8 loads) + B0,B1(T1) (4 loads); drain T0 only.
    stA(0, 0, 0); stA(0, 1, 0); stB(0, 0, 0); stB(0, 1, 0);
    stB(1, 0, 1); stB(1, 1, 1);
    asm volatile("s_waitcnt vmcnt(4)");
    __builtin_amdgcn_sched_barrier(0);
    __builtin_amdgcn_s_barrier();

    bf16x8 at[8], ab[8], bl[4], br[4];
    for (int it = 0; it < (NT >> 1); ++it) {
        const int t1 = 2 * it + 1;
        int t2 = 2 * it + 2; if (t2 >= NT) t2 -= NT;  // wrap: harmless restage
        int t3 = 2 * it + 3; if (t3 >= NT) t3 -= NT;

        // ============ K-tile T0 (buf 0) ============
        // P1: read at(8)+bl(4); stage A0(T1); MFMA Q0
#pragma unroll
        for (int i = 0; i < 4; ++i) { at[2 * i] = ldA(0, i, 0); at[2 * i + 1] = ldA(0, i, 1); }
#pragma unroll
        for (int j = 0; j < 2; ++j) { bl[2 * j] = ldB(0, j, 0); bl[2 * j + 1] = ldB(0, j, 1); }
        stA(1, 0, t1);
        PH_SYNC();
        __builtin_amdgcn_s_setprio(1);
#pragma unroll
        for (int i = 0; i < 4; ++i)
#pragma unroll
            for (int j = 0; j < 2; ++j)
#pragma unroll
                for (int kh = 0; kh < 2; ++kh)
                    acc[i][j] = __builtin_amdgcn_mfma_f32_16x16x32_bf16(
                        at[2 * i + kh], bl[2 * j + kh], acc[i][j], 0, 0, 0);
        __builtin_amdgcn_s_setprio(0);
        __builtin_amdgcn_s_barrier();
        // P2: read br(4); stage A1(T1); MFMA Q1
#pragma unroll
        for (int j = 0; j < 2; ++j) { br[2 * j] = ldB(0, j + 2, 0); br[2 * j + 1] = ldB(0, j + 2, 1); }
        stA(1, 1, t1);
        PH_SYNC();
        __builtin_amdgcn_s_setprio(1);
#pragma unroll
        for (int i = 0; i < 4; ++i)
#pragma unroll
            for (int j = 0; j < 2; ++j)
#pragma unroll
                for (int kh = 0; kh < 2; ++kh)
                    acc[i][j + 2] = __builtin_amdgcn_mfma_f32_16x16x32_bf16(
                        at[2 * i + kh], br[2 * j + kh], acc[i][j + 2], 0, 0, 0);
        __builtin_amdgcn_s_setprio(0);
        __builtin_amdgcn_s_barrier();
        // P3: read ab(8); stage B0(T2); MFMA Q2
#pragma unroll
        for (int i = 0; i < 4; ++i) { ab[2 * i] = ldA(0, i + 4, 0); ab[2 * i + 1] = ldA(0, i + 4, 1); }
        stB(0, 0, t2);
        PH_SYNC();
        __builtin_amdgcn_s_setprio(1);
#pragma unroll
        for (int i = 0; i < 4; ++i)
#pragma unroll
            for (int j = 0; j < 2; ++j)
#pragma unroll
                for (int kh = 0; kh < 2; ++kh)
                    acc[i + 4][j] = __builtin_amdgcn_mfma_f32_16x16x32_bf16(
                        ab[2 * i + kh], bl[2 * j + kh], acc[i + 4][j], 0, 0, 0);
        __builtin_amdgcn_s_setprio(0);
        __builtin_amdgcn_s_barrier();
        // P4: stage B1(T2); MFMA Q3; counted vmcnt -> buf1 (T1) landed
        stB(0, 1, t2);
        PH_SYNC();
        __builtin_amdgcn_s_setprio(1);
#pragma unroll
        for (int i = 0; i < 4; ++i)
#pragma unroll
            for (int j = 0; j < 2; ++j)
#pragma unroll
                for (int kh = 0; kh < 2; ++kh)
                    acc[i + 4][j + 2] = __builtin_amdgcn_mfma_f32_16x16x32_bf16(
                        ab[2 * i + kh], br[2 * j + kh], acc[i + 4][j + 2], 0, 0, 0);
        __builtin_amdgcn_s_setprio(0);
        asm volatile("s_waitcnt vmcnt(4)");
        __builtin_amdgcn_sched_barrier(0);
        __builtin_amdgcn_s_barrier();

        // ============ K-tile T1 (buf 1) ============
        // P5: read at+bl; stage A0(T2); MFMA Q0
#pragma unroll
        for (int i = 0; i < 4; ++i) { at[2 * i] = ldA(1, i, 0); at[2 * i + 1] = ldA(1, i, 1); }
#pragma unroll
        for (int j = 0; j < 2; ++j) { bl[2 * j] = ldB(1, j, 0); bl[2 * j + 1] = ldB(1, j, 1); }
        stA(0, 0, t2);
        PH_SYNC();
        __builtin_amdgcn_s_setprio(1);
#pragma unroll
        for (int i = 0; i < 4; ++i)
#pragma unroll
            for (int j = 0; j < 2; ++j)
#pragma unroll
                for (int kh = 0; kh < 2; ++kh)
                    acc[i][j] = __builtin_amdgcn_mfma_f32_16x16x32_bf16(
                        at[2 * i + kh], bl[2 * j + kh], acc[i][j], 0, 0, 0);
        __builtin_amdgcn_s_setprio(0);
        __builtin_amdgcn_s_barrier();
        // P6: read br; stage A1(T2); MFMA Q1
#pragma unroll
        for (int j = 0; j < 2; ++j) { br[2 * j] = ldB(1, j + 2, 0); br[2 * j + 1] = ldB(1, j + 2, 1); }
        stA(0, 1, t2);
        PH_SYNC();
        __builtin_amdgcn_s_setprio(1);
#pragma unroll
        for (int i = 0; i < 4; ++i)
#pragma unroll
            for (int j = 0; j < 2; ++j)
#pragma unroll
                for (int kh = 0; kh < 2; ++kh)
                    acc[i][j + 2] = __builtin_amdgcn_mfma_f32_16x16x32_bf16(
                        at[2 * i + kh], br[2 * j + kh], acc[i][j + 2], 0, 0, 0);
        __builtin_amdgcn_s_setprio(0);
        __builtin_amdgcn_s_barrier();
        // P7: read ab; stage B0(T3); MFMA Q2
#pragma unroll
        for (int i = 0; i < 4; ++i) { ab[2 * i] = ldA(1, i + 4, 0); ab[2 * i + 1] = ldA(1, i + 4, 1); }
        stB(1, 0, t3);
        PH_SYNC();
        __builtin_amdgcn_s_setprio(1);
#pragma unroll
        for (int i = 0; i < 4; ++i)
#pragma unroll
            for (int j = 0; j < 2; ++j)
#pragma unroll
                for (int kh = 0; kh < 2; ++kh)
                    acc[i + 4][j] = __builtin_amdgcn_mfma_f32_16x16x32_bf16(
                        ab[2 * i + kh], bl[2 * j + kh], acc[i + 4][j], 0, 0, 0);
        __builtin_amdgcn_s_setprio(0);
        __builtin_amdgcn_s_barrier();
        // P8: stage B1(T3); MFMA Q3; counted vmcnt -> buf0 (T2) landed
        stB(1, 1, t3);
        PH_SYNC();
        __builtin_amdgcn_s_setprio(1);
#pragma unroll
        for (int i = 0; i < 4; ++i)
#pragma unroll
            for (int j = 0; j < 2; ++j)
#pragma unroll
                for (int kh = 0; kh < 2; ++kh)
                    acc[i + 4][j + 2] = __builtin_amdgcn_mfma_f32_16x16x32_bf16(
                        ab[2 * i + kh], br[2 * j + kh], acc[i + 4][j + 2], 0, 0, 0);
        __builtin_amdgcn_s_setprio(0);
        asm volatile("s_waitcnt vmcnt(4)");
        __builtin_amdgcn_sched_barrier(0);
        __builtin_amdgcn_s_barrier();
    }
#undef PH_SYNC

    asm volatile("s_waitcnt vmcnt(0)");  // drain leftover stages
    float bv[4];
#pragma unroll
    for (int j = 0; j < 4; ++j) bv[j] = bias[colBase + wn * 64 + j * 16 + lq];
#pragma unroll
    for (int i = 0; i < 8; ++i) {
        const long grow = rowBase + wm * 128 + i * 16 + quad * 4;
#pragma unroll
        for (int j = 0; j < 4; ++j) {
            const long gcol = colBase + wn * 64 + j * 16 + lq;
#pragma unroll
            for (int r = 0; r < 4; ++r) {
                float v = acc[i][j][r] + bv[j];
                if (RELU) v = fmaxf(v, 0.f);
                if (VTRANS && gcol >= 2048) {
                    const int hh = (int)(gcol - 2048) >> 6;
                    const int dd = (int)(gcol - 2048) & 63;
                    const long rr = grow + r;
                    const int bb = (int)(rr >> 10);
                    const int sR = (int)(rr & 1023);
                    vt[(((long)bb * 16 + hh) * 64 + dd) * 1024 + sR] = f2bf(v);
                } else {
                    Cout[(grow + r) * N + gcol] = f2bf(v);
                }
            }
        }
    }
}

// ---------------------------------------------------------------------------
// Flash attention (round-7: round-5 structure + XCD-friendly block decode).
// ---------------------------------------------------------------------------
__global__ __launch_bounds__(256, 4) void attn_kernel(
    const u16* __restrict__ QKV, const u16* __restrict__ Vt,
    const int* __restrict__ mask, u16* __restrict__ Out) {
    __shared__ u16 KL[4096];
    __shared__ u16 VL[4096];
    __shared__ u16 PL[4][16 * 72];
    const int tid = threadIdx.x;
    const int wid = tid >> 6;
    const int lane = tid & 63;
    const int quad = lane >> 4;
    const int lq = lane & 15;
    const int slot0 = quad ^ (lq & 7);
    const int slot1 = slot0 ^ 4;

    const int bid = blockIdx.x;
    const int qb = bid >> 7;        // SLOW dim: q-block
    const int h = bid & 15;         // fast dims: (b,h) -> same XCD for all qb
    const int b = (bid >> 4) & 7;
    const int qbase = qb * 128 + wid * 32;

    bf16x8 aq[2][2];
#pragma unroll
    for (int t = 0; t < 2; ++t) {
        const u16* qp = QKV + ((long)(b * 1024 + qbase + t * 16 + lq)) * 3072 +
                        h * 64 + quad * 8;
        aq[t][0] = *(const bf16x8*)qp;
        aq[t][1] = *(const bf16x8*)(qp + 32);
    }

    const int c0 = tid, c1 = 256 + tid;
    const int r0 = c0 >> 3, j0 = (c0 & 7) ^ (r0 & 7);
    const int r1 = c1 >> 3, j1 = (c1 & 7) ^ (r1 & 7);
    const u16* srcK0 = QKV + ((long)(b * 1024 + r0)) * 3072 + 1024 + h * 64 + j0 * 8;
    const u16* srcK1 = QKV + ((long)(b * 1024 + r1)) * 3072 + 1024 + h * 64 + j1 * 8;
    const u16* srcV0 = Vt + ((long)(b * 16 + h) * 64 + r0) * 1024 + j0 * 8;
    const u16* srcV1 = Vt + ((long)(b * 16 + h) * 64 + r1) * 1024 + j1 * 8;
    u16* ldsK0 = KL + wid * 512;
    u16* ldsK1 = KL + 2048 + wid * 512;
    u16* ldsV0 = VL + wid * 512;
    u16* ldsV1 = VL + 2048 + wid * 512;

    const f32x4 fzero = {0.f, 0.f, 0.f, 0.f};
    f32x4 acc[2][4];
#pragma unroll
    for (int t = 0; t < 2; ++t)
#pragma unroll
        for (int j = 0; j < 4; ++j) acc[t][j] = fzero;
    float lsum[2][4] = {{0.f, 0.f, 0.f, 0.f}, {0.f, 0.f, 0.f, 0.f}};
    u16* myP = PL[wid];
    const int* mrow = mask + b * 1024;

    for (int kt = 0; kt < 1024; kt += 64) {
        __syncthreads();
        async_copy16(ldsK0, srcK0 + (long)kt * 3072);
        async_copy16(ldsK1, srcK1 + (long)kt * 3072);
        async_copy16(ldsV0, srcV0 + kt);
        async_copy16(ldsV1, srcV1 + kt);
        __syncthreads();

        bf16x8 kf0[4], kf1[4];
#pragma unroll
        for (int ct = 0; ct < 4; ++ct) {
            const int rowb = (ct * 16 + lq) * 64;
            kf0[ct] = *(const bf16x8*)&KL[rowb + slot0 * 8];
            kf1[ct] = *(const bf16x8*)&KL[rowb + slot1 * 8];
        }
        float mw[4];
#pragma unroll
        for (int ct = 0; ct < 4; ++ct) mw[ct] = mrow[kt + ct * 16 + lq] ? 1.f : 0.f;

#pragma unroll
        for (int t = 0; t < 2; ++t) {
            f32x4 s[4];
#pragma unroll
            for (int ct = 0; ct < 4; ++ct) {
                s[ct] = __builtin_amdgcn_mfma_f32_16x16x32_bf16(aq[t][0], kf0[ct],
                                                                fzero, 0, 0, 0);
                s[ct] = __builtin_amdgcn_mfma_f32_16x16x32_bf16(aq[t][1], kf1[ct],
                                                                s[ct], 0, 0, 0);
            }
            asm volatile("s_waitcnt lgkmcnt(0)" ::: "memory");
#pragma unroll
            for (int ct = 0; ct < 4; ++ct)
#pragma unroll
                for (int r = 0; r < 4; ++r) {
                    const float p = mw[ct] * __expf(s[ct][r] * 0.125f);
                    lsum[t][r] += p;
                    myP[(quad * 4 + r) * 72 + ct * 16 + lq] = f2bf_fast(p);
                }
            asm volatile("s_waitcnt lgkmcnt(0)" ::: "memory");
            const bf16x8 pf0 = *(const bf16x8*)&myP[lq * 72 + quad * 8];
            const bf16x8 pf1 = *(const bf16x8*)&myP[lq * 72 + 32 + quad * 8];
#pragma unroll
            for (int j = 0; j < 4; ++j) {
                const int rowb = (j * 16 + lq) * 64;
                const bf16x8 vf0 = *(const bf16x8*)&VL[rowb + slot0 * 8];
                const bf16x8 vf1 = *(const bf16x8*)&VL[rowb + slot1 * 8];
                acc[t][j] = __builtin_amdgcn_mfma_f32_16x16x32_bf16(pf0, vf0,
                                                                    acc[t][j], 0, 0, 0);
                acc[t][j] = __builtin_amdgcn_mfma_f32_16x16x32_bf16(pf1, vf1,
                                                                    acc[t][j], 0, 0, 0);
            }
        }
    }

#pragma unroll
    for (int t = 0; t < 2; ++t) {
        float inv[4];
#pragma unroll
        for (int r = 0; r < 4; ++r) {
            float l = lsum[t][r];
#pragma unroll
            for (int off = 1; off < 16; off <<= 1) l += __shfl_xor(l, off, 16);
            inv[r] = 1.f / l;
        }
        const long orow = (long)b * 1024 + qbase + t * 16 + quad * 4;
#pragma unroll
        for (int j = 0; j < 4; ++j)
#pragma unroll
            for (int r = 0; r < 4; ++r)
                Out[(orow + r) * 1024 + h * 64 + j * 16 + lq] =
                    f2bf_fast(acc[t][j][r] * inv[r]);
    }
}

// ---------------------------------------------------------------------------
extern "C" void kernel_launch(void* const* d_in, const int* in_sizes, int n_in,
                              void* d_out, int out_size, void* d_ws, size_t ws_size,
                              hipStream_t stream) {
    const float* we        = (const float*)d_in[0];
    const int*   amask     = (const int*)d_in[1];
    const int*   span_b    = (const int*)d_in[2];
    const int*   span_s    = (const int*)d_in[3];
    const int*   span_t    = (const int*)d_in[4];
    const float* tag_emb   = (const float*)d_in[5];
    const float* gate_w    = (const float*)d_in[6];
    const float* gate_b    = (const float*)d_in[7];
    const float* attn_ln_g = (const float*)d_in[8];
    const float* attn_ln_b = (const float*)d_in[9];
    const float* in_proj_w = (const float*)d_in[10];
    const float* in_proj_b = (const float*)d_in[11];
    const float* out_proj_w= (const float*)d_in[12];
    const float* out_proj_b= (const float*)d_in[13];
    const float* enc1_g    = (const float*)d_in[14];
    const float* enc1_b    = (const float*)d_in[15];
    const float* lin1_w    = (const float*)d_in[16];
    const float* lin1_b    = (const float*)d_in[17];
    const float* lin2_w    = (const float*)d_in[18];
    const float* lin2_b    = (const float*)d_in[19];
    const float* enc2_g    = (const float*)d_in[20];
    const float* enc2_b    = (const float*)d_in[21];
    float* out = (float*)d_out;  // also fp32 scratch (h1/h2)

    char* ws = (char*)d_ws;
    size_t off = 0;
    auto alloc = [&](size_t bytes) {
        void* p = ws + off;
        off += (bytes + 255) & ~(size_t)255;
        return p;
    };
    const size_t MT = 8192;
    u16* oe_bf   = (u16*)alloc(MT * 1024 * 2);
    u16* ax_bf   = (u16*)alloc(MT * 1024 * 2);
    char* region = (char*)alloc((size_t)67108864);             // qkv+vt | ff1
    u16* qkv_bf  = (u16*)region;
    u16* vt_bf   = (u16*)(region + (size_t)MT * 3072 * 2);
    u16* ff1_bf  = (u16*)region;
    u16* wb_inproj  = (u16*)alloc((size_t)3072 * 1024 * 2);
    u16* wb_outproj = (u16*)alloc((size_t)1024 * 1024 * 2);
    u16* wb_lin1    = (u16*)alloc((size_t)4096 * 1024 * 2);
    u16* wb_lin2    = (u16*)alloc((size_t)1024 * 4096 * 2);

    // 1. prep: lnspan (8192 blocks) + 4x weight f2bf (12288 blocks)
    prep_kernel<<<20480, 256, 0, stream>>>(
        we, span_b, span_s, span_t, tag_emb, gate_w, gate_b,
        attn_ln_g, attn_ln_b, in_proj_w, out_proj_w, lin1_w, lin2_w,
        oe_bf, wb_inproj, wb_outproj, wb_lin1, wb_lin2);
    // 2. QKV projection (8-phase 256^2); V columns written transposed
    dim3 g1(32, 12);
    gemm_nt8<false, true><<<g1, 512, 0, stream>>>(
        oe_bf, wb_inproj, in_proj_b, qkv_bf, 3072, 1024, vt_bf);
    // 3. attention
    attn_kernel<<<1024, 256, 0, stream>>>(qkv_bf, vt_bf, amask, ax_bf);
    // 4. out-proj + residual (fp32 out)
    dim3 g2(64, 8);
    gemm_nt<false, false, true, false><<<g2, 256, 0, stream>>>(
        ax_bf, wb_outproj, out_proj_b, oe_bf, out, 1024, 1024, nullptr);
    // 5. LN enc1 -> bf16
    ln_kernel<false, true, false><<<8192, 256, 0, stream>>>(
        out, enc1_g, enc1_b, 1e-5f, nullptr, ax_bf, nullptr);
    // 6. FF1 (relu, 8-phase 256^2)
    dim3 g3(32, 16);
    gemm_nt8<true, false><<<g3, 512, 0, stream>>>(
        ax_bf, wb_lin1, lin1_b, ff1_bf, 4096, 1024, nullptr);
    // 7. FF2 + residual (fp32 out)
    gemm_nt<false, false, true, false><<<g2, 256, 0, stream>>>(
        ff1_bf, wb_lin2, lin2_b, ax_bf, out, 1024, 4096, nullptr);
    // 8. final LN + out_emb addend
    ln_kernel<true, false, true><<<8192, 256, 0, stream>>>(
        out, enc2_g, enc2_b, 1e-5f, out, nullptr, oe_bf);
}

// Round 9
// 473.860 us; speedup vs baseline: 1.1016x; 1.1016x over previous
//
#include <hip/hip_runtime.h>

#define DEV __device__ __forceinline__

typedef short bf16x8 __attribute__((ext_vector_type(8)));
typedef float f32x4 __attribute__((ext_vector_type(4)));
typedef unsigned short u16;
typedef unsigned int u32;
typedef unsigned long long u64;

typedef __attribute__((address_space(3))) void lds_void;
typedef __attribute__((address_space(1))) void gbl_void;

DEV void async_copy16(void* lds_dst, const void* g_src) {
    __builtin_amdgcn_global_load_lds((gbl_void*)g_src, (lds_void*)lds_dst, 16, 0, 0);
}

DEV u16 f2bf(float x) {
    u32 u = __float_as_uint(x);
    return (u16)((u + 0x7fffu + ((u >> 16) & 1u)) >> 16);
}
DEV u16 f2bf_fast(float x) {  // x >= 0, finite
    return (u16)((__float_as_uint(x) + 0x8000u) >> 16);
}
DEV float bf2f(u16 v) { return __uint_as_float(((u32)v) << 16); }

// ---------------------------------------------------------------------------
// PREP mega-kernel: one dispatch replacing {zero, rowlist, f2bf x4, lnspan}.
// Blocks [0,8192):      fused span-scatter + attn-LN (one block per row).
// Blocks [8192,20480):  fp32->bf16 weight conversion, 4 segments.
// ---------------------------------------------------------------------------
__global__ __launch_bounds__(256) void prep_kernel(
    const float* __restrict__ we, const int* __restrict__ sb,
    const int* __restrict__ ss, const int* __restrict__ stg,
    const float* __restrict__ tag_emb, const float* __restrict__ gate_w,
    const float* __restrict__ gate_b, const float* __restrict__ g,
    const float* __restrict__ bta,
    const float* __restrict__ w0, const float* __restrict__ w1,
    const float* __restrict__ w2, const float* __restrict__ w3,
    u16* __restrict__ oe_bf, u16* __restrict__ o0, u16* __restrict__ o1,
    u16* __restrict__ o2, u16* __restrict__ o3) {
    const int blk = blockIdx.x;
    const int t = threadIdx.x;

    if (blk >= 8192) {  // ---- weight f2bf segments ----
        int base = blk - 8192;
        const float* src; u16* dst;
        if (base < 3072)      { src = w0; dst = o0; }
        else if (base < 4096) { src = w1; dst = o1; base -= 3072; }
        else if (base < 8192) { src = w2; dst = o2; base -= 4096; }
        else                  { src = w3; dst = o3; base -= 8192; }
        const int i = base * 256 + t;
        const float4 v = ((const float4*)src)[i];
        ushort4 o;
        o.x = f2bf(v.x); o.y = f2bf(v.y); o.z = f2bf(v.z); o.w = f2bf(v.w);
        ((ushort4*)dst)[i] = o;
        return;
    }

    // ---- lnspan ----
    __shared__ float red[8];
    __shared__ u64 smask[8];
    const int row = blk;
    const int b = row >> 10;
    const int s = row & 1023;

    {   // span scan: thread t checks spans t and t+256
        const bool m0 = (sb[t] == b) && ((u32)(s - ss[t]) < 32u);
        const bool m1 = (sb[t + 256] == b) && ((u32)(s - ss[t + 256]) < 32u);
        const u64 b0 = __ballot(m0);
        const u64 b1 = __ballot(m1);
        if ((t & 63) == 0) { smask[t >> 6] = b0; smask[4 + (t >> 6)] = b1; }
    }

    float4 x = ((const float4*)(we + (long)row * 1024))[t];
    const float4 gw = ((const float4*)gate_w)[t];
    float dot;
    {   // RoPE pairs p0=2t, p1=2t+1; dot with gate_w
        const float p0 = (float)(2 * t);
        const float p1 = (float)(2 * t + 1);
        const float inv0 = exp2f(p0 * (-13.287712379549449f / 512.0f));
        const float inv1 = exp2f(p1 * (-13.287712379549449f / 512.0f));
        const float a0 = (float)s * inv0, a1 = (float)s * inv1;
        const float s0 = sinf(a0), c0 = cosf(a0);
        const float s1 = sinf(a1), c1 = cosf(a1);
        const float r1a = x.x * c0 - x.y * s0, r2a = x.x * s0 + x.y * c0;
        const float r1b = x.z * c1 - x.w * s1, r2b = x.z * s1 + x.w * c1;
        dot = r1a * gw.x + r2a * gw.y + r1b * gw.z + r2b * gw.w;
    }
#pragma unroll
    for (int off = 32; off > 0; off >>= 1) dot += __shfl_xor(dot, off, 64);
    if ((t & 63) == 0) red[t >> 6] = dot;
    __syncthreads();  // red + smask visible
    const float z = red[0] + red[1] + red[2] + red[3] + gate_b[0];
    const float gate = 0.25f + 0.5f / (1.f + __expf(-z));
    const float coef = gate * 16.f;  // L * TAG_RATE * gate

    float4 add = {0.f, 0.f, 0.f, 0.f};
#pragma unroll
    for (int gi = 0; gi < 8; ++gi) {
        u64 m = smask[gi];
        const int nb = (gi & 3) * 64 + (gi >> 2) * 256;
        while (m) {
            const int bit = __ffsll(m) - 1;
            m &= m - 1;
            const int tag = stg[nb + bit];
            const float4 te = ((const float4*)(tag_emb + (long)tag * 1024))[t];
            add.x += te.x; add.y += te.y; add.z += te.z; add.w += te.w;
        }
    }
    x.x += coef * add.x; x.y += coef * add.y;
    x.z += coef * add.z; x.w += coef * add.w;

    // LayerNorm (eps = 1e-12)
    __syncthreads();
    float sm = x.x + x.y + x.z + x.w;
#pragma unroll
    for (int off = 32; off > 0; off >>= 1) sm += __shfl_xor(sm, off, 64);
    if ((t & 63) == 0) red[t >> 6] = sm;
    __syncthreads();
    const float mean = (red[0] + red[1] + red[2] + red[3]) * (1.f / 1024.f);
    float4 dx;
    dx.x = x.x - mean; dx.y = x.y - mean; dx.z = x.z - mean; dx.w = x.w - mean;
    float ss2 = dx.x * dx.x + dx.y * dx.y + dx.z * dx.z + dx.w * dx.w;
#pragma unroll
    for (int off = 32; off > 0; off >>= 1) ss2 += __shfl_xor(ss2, off, 64);
    if ((t & 63) == 0) red[4 + (t >> 6)] = ss2;
    __syncthreads();
    const float var = (red[4] + red[5] + red[6] + red[7]) * (1.f / 1024.f);
    const float rstd = rsqrtf(var + 1e-12f);
    const float4 gv = ((const float4*)g)[t];
    const float4 bv = ((const float4*)bta)[t];
    ushort4 o;
    o.x = f2bf(dx.x * rstd * gv.x + bv.x);
    o.y = f2bf(dx.y * rstd * gv.y + bv.y);
    o.z = f2bf(dx.z * rstd * gv.z + bv.z);
    o.w = f2bf(dx.w * rstd * gv.w + bv.w);
    ((ushort4*)(oe_bf + (long)row * 1024))[t] = o;
}

// ---------------------------------------------------------------------------
// LayerNorm over D=1024, one block per row.
// ---------------------------------------------------------------------------
template <bool WRITE_F32, bool WRITE_BF, bool FINAL>
__global__ __launch_bounds__(256) void ln_kernel(
    const float* __restrict__ X, const float* __restrict__ g,
    const float* __restrict__ bta, float eps, float* __restrict__ Yf,
    u16* __restrict__ Ybf, const u16* __restrict__ addend) {
    __shared__ float red[8];
    const long row = blockIdx.x;
    const int t = threadIdx.x;
    const float4 x = ((const float4*)(X + row * 1024))[t];
    float s = x.x + x.y + x.z + x.w;
#pragma unroll
    for (int off = 32; off > 0; off >>= 1) s += __shfl_xor(s, off, 64);
    if ((t & 63) == 0) red[t >> 6] = s;
    __syncthreads();
    const float mean = (red[0] + red[1] + red[2] + red[3]) * (1.f / 1024.f);
    float4 dx;
    dx.x = x.x - mean; dx.y = x.y - mean; dx.z = x.z - mean; dx.w = x.w - mean;
    float ss = dx.x * dx.x + dx.y * dx.y + dx.z * dx.z + dx.w * dx.w;
#pragma unroll
    for (int off = 32; off > 0; off >>= 1) ss += __shfl_xor(ss, off, 64);
    if ((t & 63) == 0) red[4 + (t >> 6)] = ss;
    __syncthreads();
    const float var = (red[4] + red[5] + red[6] + red[7]) * (1.f / 1024.f);
    const float rstd = rsqrtf(var + eps);
    const float4 gv = ((const float4*)g)[t];
    const float4 bv = ((const float4*)bta)[t];
    float4 y;
    y.x = dx.x * rstd * gv.x + bv.x;
    y.y = dx.y * rstd * gv.y + bv.y;
    y.z = dx.z * rstd * gv.z + bv.z;
    y.w = dx.w * rstd * gv.w + bv.w;
    if (FINAL) {
        const ushort4 a = ((const ushort4*)(addend + row * 1024))[t];
        y.x += bf2f(a.x); y.y += bf2f(a.y); y.z += bf2f(a.z); y.w += bf2f(a.w);
    }
    if (WRITE_F32) ((float4*)(Yf + row * 1024))[t] = y;
    if (WRITE_BF) {
        ushort4 o;
        o.x = f2bf(y.x); o.y = f2bf(y.y); o.z = f2bf(y.z); o.w = f2bf(y.w);
        ((ushort4*)(Ybf + row * 1024))[t] = o;
    }
}

// ---------------------------------------------------------------------------
// NT GEMM (measured-best structure): 16x16x32 MFMA, 4x4 acc/wave, 128x128
// tile, BK=64, XOR slot-swizzled LDS, 32KB LDS -> 2 blocks/CU.
// Session verdict: this 2-barrier 128^2 structure is the plateau winner
// (~870 TF / 36% MfmaUtil). Three 256^2 8-phase ports (r1/r3/r8) all
// underperformed it (716 TF / 830 TF / 490 TF) -> do not revisit.
// VTRANS: for the QKV GEMM, output columns >= 2048 (the V head block) are
// written directly TRANSPOSED into vt[b,h,d,s].
// ---------------------------------------------------------------------------
template <bool OUT_BF16, bool RELU, bool HAS_RES, bool VTRANS>
__global__ __launch_bounds__(256, 2) void gemm_nt(
    const u16* __restrict__ A, const u16* __restrict__ B,
    const float* __restrict__ bias, const u16* __restrict__ res,
    void* __restrict__ Cout, int N, int K, u16* __restrict__ vt) {
    __shared__ u16 Al[8192];   // 128 rows x 64 k = 16 KB
    __shared__ u16 Bl[8192];
    const int tid = threadIdx.x;
    const int wave = tid >> 6;
    const int lane = tid & 63;
    const int quad = lane >> 4;
    const int lq = lane & 15;
    const int wm = wave >> 1;
    const int wn = wave & 1;
    const long rowBase = (long)blockIdx.x * 128;
    const long colBase = (long)blockIdx.y * 128;

    f32x4 acc[4][4];
    const f32x4 fzero = {0.f, 0.f, 0.f, 0.f};
#pragma unroll
    for (int i = 0; i < 4; ++i)
#pragma unroll
        for (int j = 0; j < 4; ++j) acc[i][j] = fzero;

    const int rX = tid >> 3;
    const int pX = (tid & 7) ^ (rX & 7);
    const u16* gA = A + (rowBase + rX) * (long)K + pX * 8;
    const u16* gB = B + (colBase + rX) * (long)K + pX * 8;
    u16* ldsA = Al + wave * 512;
    u16* ldsB = Bl + wave * 512;

    for (int kt = 0; kt < K; kt += 64) {
        __syncthreads();
#pragma unroll
        for (int c = 0; c < 4; ++c) {
            async_copy16(ldsA + c * 2048, gA + (long)c * 32 * K + kt);
            async_copy16(ldsB + c * 2048, gB + (long)c * 32 * K + kt);
        }
        __syncthreads();
#pragma unroll
        for (int ks = 0; ks < 2; ++ks) {
            bf16x8 af[4], bfr[4];
#pragma unroll
            for (int i = 0; i < 4; ++i) {
                const int r = wm * 64 + i * 16 + lq;
                af[i] = *(const bf16x8*)&Al[r * 64 + (((ks * 4 + quad) ^ (lq & 7)) * 8)];
            }
#pragma unroll
            for (int j = 0; j < 4; ++j) {
                const int r = wn * 64 + j * 16 + lq;
                bfr[j] = *(const bf16x8*)&Bl[r * 64 + (((ks * 4 + quad) ^ (lq & 7)) * 8)];
            }
#pragma unroll
            for (int i = 0; i < 4; ++i)
#pragma unroll
                for (int j = 0; j < 4; ++j)
                    acc[i][j] = __builtin_amdgcn_mfma_f32_16x16x32_bf16(
                        af[i], bfr[j], acc[i][j], 0, 0, 0);
        }
    }

    float biasv[4];
#pragma unroll
    for (int j = 0; j < 4; ++j) biasv[j] = bias[colBase + wn * 64 + j * 16 + lq];
#pragma unroll
    for (int i = 0; i < 4; ++i) {
        const long grow = rowBase + wm * 64 + i * 16 + quad * 4;
#pragma unroll
        for (int j = 0; j < 4; ++j) {
            const long gcol = colBase + wn * 64 + j * 16 + lq;
#pragma unroll
            for (int r = 0; r < 4; ++r) {
                float v = acc[i][j][r] + biasv[j];
                if (RELU) v = fmaxf(v, 0.f);
                if (HAS_RES) v += bf2f(res[(grow + r) * N + gcol]);
                if (VTRANS && gcol >= 2048) {
                    const int hh = (int)(gcol - 2048) >> 6;
                    const int dd = (int)(gcol - 2048) & 63;
                    const long rr = grow + r;
                    const int bb = (int)(rr >> 10);
                    const int sR = (int)(rr & 1023);
                    vt[(((long)bb * 16 + hh) * 64 + dd) * 1024 + sR] = f2bf(v);
                } else if (OUT_BF16) {
                    ((u16*)Cout)[(grow + r) * N + gcol] = f2bf(v);
                } else {
                    ((float*)Cout)[(grow + r) * N + gcol] = v;
                }
            }
        }
    }
}

// ---------------------------------------------------------------------------
// Flash attention (round-5 best-measured configuration, verbatim).
// ---------------------------------------------------------------------------
__global__ __launch_bounds__(256, 4) void attn_kernel(
    const u16* __restrict__ QKV, const u16* __restrict__ Vt,
    const int* __restrict__ mask, u16* __restrict__ Out) {
    __shared__ u16 KL[4096];
    __shared__ u16 VL[4096];
    __shared__ u16 PL[4][16 * 72];
    const int tid = threadIdx.x;
    const int wid = tid >> 6;
    const int lane = tid & 63;
    const int quad = lane >> 4;
    const int lq = lane & 15;
    const int slot0 = quad ^ (lq & 7);
    const int slot1 = slot0 ^ 4;

    const int bid = blockIdx.x;
    const int qb = bid & 7;
    const int h = (bid >> 3) & 15;
    const int b = bid >> 7;
    const int qbase = qb * 128 + wid * 32;

    bf16x8 aq[2][2];
#pragma unroll
    for (int t = 0; t < 2; ++t) {
        const u16* qp = QKV + ((long)(b * 1024 + qbase + t * 16 + lq)) * 3072 +
                        h * 64 + quad * 8;
        aq[t][0] = *(const bf16x8*)qp;
        aq[t][1] = *(const bf16x8*)(qp + 32);
    }

    const int c0 = tid, c1 = 256 + tid;
    const int r0 = c0 >> 3, j0 = (c0 & 7) ^ (r0 & 7);
    const int r1 = c1 >> 3, j1 = (c1 & 7) ^ (r1 & 7);
    const u16* srcK0 = QKV + ((long)(b * 1024 + r0)) * 3072 + 1024 + h * 64 + j0 * 8;
    const u16* srcK1 = QKV + ((long)(b * 1024 + r1)) * 3072 + 1024 + h * 64 + j1 * 8;
    const u16* srcV0 = Vt + ((long)(b * 16 + h) * 64 + r0) * 1024 + j0 * 8;
    const u16* srcV1 = Vt + ((long)(b * 16 + h) * 64 + r1) * 1024 + j1 * 8;
    u16* ldsK0 = KL + wid * 512;
    u16* ldsK1 = KL + 2048 + wid * 512;
    u16* ldsV0 = VL + wid * 512;
    u16* ldsV1 = VL + 2048 + wid * 512;

    const f32x4 fzero = {0.f, 0.f, 0.f, 0.f};
    f32x4 acc[2][4];
#pragma unroll
    for (int t = 0; t < 2; ++t)
#pragma unroll
        for (int j = 0; j < 4; ++j) acc[t][j] = fzero;
    float lsum[2][4] = {{0.f, 0.f, 0.f, 0.f}, {0.f, 0.f, 0.f, 0.f}};
    u16* myP = PL[wid];
    const int* mrow = mask + b * 1024;

    for (int kt = 0; kt < 1024; kt += 64) {
        __syncthreads();
        async_copy16(ldsK0, srcK0 + (long)kt * 3072);
        async_copy16(ldsK1, srcK1 + (long)kt * 3072);
        async_copy16(ldsV0, srcV0 + kt);
        async_copy16(ldsV1, srcV1 + kt);
        __syncthreads();

        bf16x8 kf0[4], kf1[4];
#pragma unroll
        for (int ct = 0; ct < 4; ++ct) {
            const int rowb = (ct * 16 + lq) * 64;
            kf0[ct] = *(const bf16x8*)&KL[rowb + slot0 * 8];
            kf1[ct] = *(const bf16x8*)&KL[rowb + slot1 * 8];
        }
        float mw[4];
#pragma unroll
        for (int ct = 0; ct < 4; ++ct) mw[ct] = mrow[kt + ct * 16 + lq] ? 1.f : 0.f;

#pragma unroll
        for (int t = 0; t < 2; ++t) {
            f32x4 s[4];
#pragma unroll
            for (int ct = 0; ct < 4; ++ct) {
                s[ct] = __builtin_amdgcn_mfma_f32_16x16x32_bf16(aq[t][0], kf0[ct],
                                                                fzero, 0, 0, 0);
                s[ct] = __builtin_amdgcn_mfma_f32_16x16x32_bf16(aq[t][1], kf1[ct],
                                                                s[ct], 0, 0, 0);
            }
            asm volatile("s_waitcnt lgkmcnt(0)" ::: "memory");
#pragma unroll
            for (int ct = 0; ct < 4; ++ct)
#pragma unroll
                for (int r = 0; r < 4; ++r) {
                    const float p = mw[ct] * __expf(s[ct][r] * 0.125f);
                    lsum[t][r] += p;
                    myP[(quad * 4 + r) * 72 + ct * 16 + lq] = f2bf_fast(p);
                }
            asm volatile("s_waitcnt lgkmcnt(0)" ::: "memory");
            const bf16x8 pf0 = *(const bf16x8*)&myP[lq * 72 + quad * 8];
            const bf16x8 pf1 = *(const bf16x8*)&myP[lq * 72 + 32 + quad * 8];
#pragma unroll
            for (int j = 0; j < 4; ++j) {
                const int rowb = (j * 16 + lq) * 64;
                const bf16x8 vf0 = *(const bf16x8*)&VL[rowb + slot0 * 8];
                const bf16x8 vf1 = *(const bf16x8*)&VL[rowb + slot1 * 8];
                acc[t][j] = __builtin_amdgcn_mfma_f32_16x16x32_bf16(pf0, vf0,
                                                                    acc[t][j], 0, 0, 0);
                acc[t][j] = __builtin_amdgcn_mfma_f32_16x16x32_bf16(pf1, vf1,
                                                                    acc[t][j], 0, 0, 0);
            }
        }
    }

#pragma unroll
    for (int t = 0; t < 2; ++t) {
        float inv[4];
#pragma unroll
        for (int r = 0; r < 4; ++r) {
            float l = lsum[t][r];
#pragma unroll
            for (int off = 1; off < 16; off <<= 1) l += __shfl_xor(l, off, 16);
            inv[r] = 1.f / l;
        }
        const long orow = (long)b * 1024 + qbase + t * 16 + quad * 4;
#pragma unroll
        for (int j = 0; j < 4; ++j)
#pragma unroll
            for (int r = 0; r < 4; ++r)
                Out[(orow + r) * 1024 + h * 64 + j * 16 + lq] =
                    f2bf_fast(acc[t][j][r] * inv[r]);
    }
}

// ---------------------------------------------------------------------------
extern "C" void kernel_launch(void* const* d_in, const int* in_sizes, int n_in,
                              void* d_out, int out_size, void* d_ws, size_t ws_size,
                              hipStream_t stream) {
    const float* we        = (const float*)d_in[0];
    const int*   amask     = (const int*)d_in[1];
    const int*   span_b    = (const int*)d_in[2];
    const int*   span_s    = (const int*)d_in[3];
    const int*   span_t    = (const int*)d_in[4];
    const float* tag_emb   = (const float*)d_in[5];
    const float* gate_w    = (const float*)d_in[6];
    const float* gate_b    = (const float*)d_in[7];
    const float* attn_ln_g = (const float*)d_in[8];
    const float* attn_ln_b = (const float*)d_in[9];
    const float* in_proj_w = (const float*)d_in[10];
    const float* in_proj_b = (const float*)d_in[11];
    const float* out_proj_w= (const float*)d_in[12];
    const float* out_proj_b= (const float*)d_in[13];
    const float* enc1_g    = (const float*)d_in[14];
    const float* enc1_b    = (const float*)d_in[15];
    const float* lin1_w    = (const float*)d_in[16];
    const float* lin1_b    = (const float*)d_in[17];
    const float* lin2_w    = (const float*)d_in[18];
    const float* lin2_b    = (const float*)d_in[19];
    const float* enc2_g    = (const float*)d_in[20];
    const float* enc2_b    = (const float*)d_in[21];
    float* out = (float*)d_out;  // also fp32 scratch (h1/h2)

    char* ws = (char*)d_ws;
    size_t off = 0;
    auto alloc = [&](size_t bytes) {
        void* p = ws + off;
        off += (bytes + 255) & ~(size_t)255;
        return p;
    };
    const size_t MT = 8192;
    u16* oe_bf   = (u16*)alloc(MT * 1024 * 2);
    u16* ax_bf   = (u16*)alloc(MT * 1024 * 2);
    char* region = (char*)alloc((size_t)67108864);             // qkv+vt | ff1
    u16* qkv_bf  = (u16*)region;
    u16* vt_bf   = (u16*)(region + (size_t)MT * 3072 * 2);
    u16* ff1_bf  = (u16*)region;
    u16* wb_inproj  = (u16*)alloc((size_t)3072 * 1024 * 2);
    u16* wb_outproj = (u16*)alloc((size_t)1024 * 1024 * 2);
    u16* wb_lin1    = (u16*)alloc((size_t)4096 * 1024 * 2);
    u16* wb_lin2    = (u16*)alloc((size_t)1024 * 4096 * 2);

    // 1. prep: lnspan (8192 blocks) + 4x weight f2bf (12288 blocks)
    prep_kernel<<<20480, 256, 0, stream>>>(
        we, span_b, span_s, span_t, tag_emb, gate_w, gate_b,
        attn_ln_g, attn_ln_b, in_proj_w, out_proj_w, lin1_w, lin2_w,
        oe_bf, wb_inproj, wb_outproj, wb_lin1, wb_lin2);
    // 2. QKV projection; V columns written transposed into vt_bf
    dim3 g1(64, 24);
    gemm_nt<true, false, false, true><<<g1, 256, 0, stream>>>(
        oe_bf, wb_inproj, in_proj_b, nullptr, qkv_bf, 3072, 1024, vt_bf);
    // 3. attention
    attn_kernel<<<1024, 256, 0, stream>>>(qkv_bf, vt_bf, amask, ax_bf);
    // 4. out-proj + residual (fp32 out)
    dim3 g2(64, 8);
    gemm_nt<false, false, true, false><<<g2, 256, 0, stream>>>(
        ax_bf, wb_outproj, out_proj_b, oe_bf, out, 1024, 1024, nullptr);
    // 5. LN enc1 -> bf16
    ln_kernel<false, true, false><<<8192, 256, 0, stream>>>(
        out, enc1_g, enc1_b, 1e-5f, nullptr, ax_bf, nullptr);
    // 6. FF1 (relu)
    dim3 g3(64, 32);
    gemm_nt<true, true, false, false><<<g3, 256, 0, stream>>>(
        ax_bf, wb_lin1, lin1_b, nullptr, ff1_bf, 4096, 1024, nullptr);
    // 7. FF2 + residual (fp32 out)
    gemm_nt<false, false, true, false><<<g2, 256, 0, stream>>>(
        ff1_bf, wb_lin2, lin2_b, ax_bf, out, 1024, 4096, nullptr);
    // 8. final LN + out_emb addend
    ln_kernel<true, false, true><<<8192, 256, 0, stream>>>(
        out, enc2_g, enc2_b, 1e-5f, out, nullptr, oe_bf);
}